// Round 11
// baseline (519.002 us; speedup 1.0000x reference)
//
#include <hip/hip_runtime.h>
#include <math.h>

// VariableSelectionNetwork — round 13.
// R12 banked: wave-private staging + barrier-free kloop -> vsn 306->233us
// (all three counter predictions hit). Remaining floor: LDS pipe ~68KB/kk
// (A 32K + B 32K reads + 4K writes @ ~85B/cyc ~= 800cyc/kk). B-slices are
// wave-private => LDS for B is pointless.
// FIX: B fully in REGISTERS. 4x global_load_dwordx4/kk into double-buffered
// short8 b[2][4] (32 VGPR, unroll-2, compiler-counted waitcnts; tail
// prefetches next GEMM's chunk0 — regs survive barrier drains). Halves LDS
// traffic, kills B-staging conflicts. Freed sB LDS -> sX[64][512]: x2 lives
// there (not overwriting sA) -> post-GEMM1 barrier gone (5->3+ln barriers/f).
// x2p regs dropped (gate re-reads sX) to fit the 128-reg cap.
// ctx_fused / pack_all byte-identical to R12.

#define H 512
#define NF 4
#define MTOT 32768

typedef unsigned short u16;
typedef unsigned int u32;
typedef __attribute__((ext_vector_type(8))) short short8;   // 8 bf16 = 4 VGPRs
typedef __attribute__((ext_vector_type(4))) float f32x4;    // MFMA C/D
typedef __attribute__((ext_vector_type(4))) u32 u32x4;      // packed bf16 x8

__device__ __forceinline__ u16 f2bf(float x) {
  union { float f; u32 u; } v; v.f = x;
  return (u16)((v.u + 0x7fffu + ((v.u >> 16) & 1u)) >> 16);  // RNE
}
__device__ __forceinline__ float bf2f(u32 h16) {
  union { u32 u; float f; } v; v.u = h16 << 16;
  return v.f;
}
__device__ __forceinline__ float elu_f(float x) {
  return x > 0.0f ? x : (__expf(x) - 1.0f);
}
__device__ __forceinline__ float sigmoid_f(float x) {
  return __builtin_amdgcn_rcpf(1.0f + __expf(-x));
}
// packed 2x bf16 (lo->[15:0], hi->[31:16]), RNE — matches f2bf
__device__ __forceinline__ u32 cvtpk(float lo, float hi) {
  u32 r;
  asm("v_cvt_pk_bf16_f32 %0, %1, %2" : "=v"(r) : "v"(lo), "v"(hi));
  return r;
}
// butterfly-add over 16-lane groups via DPP (VALU pipe, no LDS)
template <int CTRL>
__device__ __forceinline__ float dppadd(float v) {
  int t = __builtin_amdgcn_update_dpp(0, __float_as_int(v), CTRL, 0xF, 0xF, true);
  return v + __int_as_float(t);
}
__device__ __forceinline__ float red16(float v) {
  v = dppadd<0xB1>(v);    // xor1
  v = dppadd<0x4E>(v);    // xor2
  v = dppadd<0x141>(v);   // row_half_mirror
  v = dppadd<0x140>(v);   // row_mirror
  return v;
}

// async global->LDS, 16B per lane; LDS dest = wave-uniform base + lane*16.
__device__ __forceinline__ void glld16(const void* g, void* l) {
  __builtin_amdgcn_global_load_lds(
      (const __attribute__((address_space(1))) u32*)(unsigned long long)(uintptr_t)g,
      (__attribute__((address_space(3))) u32*)(u32)(uintptr_t)l, 16, 0, 0);
}

#define MFMA16(a, b, c) __builtin_amdgcn_mfma_f32_16x16x32_bf16((a), (b), (c), 0, 0, 0)

// x value stored in swizzled tile at logical (m,n):
__device__ __forceinline__ int sA_idx(int m, int n) {
  return m * 512 + ((((n >> 3) ^ (m & 7)) << 3) + (n & 7));
}

// device-scope grid barrier: all blocks arrive, then proceed. cnt pre-zeroed.
__device__ __forceinline__ void gridbar(u32* cnt, u32 target) {
  __syncthreads();
  __threadfence();
  if (threadIdx.x == 0) {
    __hip_atomic_fetch_add(cnt, 1u, __ATOMIC_RELEASE, __HIP_MEMORY_SCOPE_AGENT);
    while (__hip_atomic_load(cnt, __ATOMIC_ACQUIRE, __HIP_MEMORY_SCOPE_AGENT) < target)
      __builtin_amdgcn_s_sleep(8);
  }
  __syncthreads();
  __threadfence();
}

struct TileCtx {
  int tid, wid, lane, quad, col;
};

// ---------------- pack_all: all 11 matrices + barrier-counter reset. -------
__global__ __launch_bounds__(256)
void pack_all(const float* __restrict__ W2, const float* __restrict__ Wg,
              const float* __restrict__ W1c, const float* __restrict__ W2c,
              const float* __restrict__ Wgc,
              u16* __restrict__ W2p, u16* __restrict__ Wgp, u16* __restrict__ Cp,
              u32* __restrict__ bar) {
  int g = blockIdx.x * 256 + threadIdx.x;       // 0 .. 11*32768-1
  if (g == 0) { bar[0] = 0; bar[1] = 0; }
  int r = g & 32767; int mat = g >> 15;
  if (mat >= 11) return;
  const float* src; u16* dst;
  if (mat < 4)      { src = W2 + (size_t)mat * 262144;       dst = W2p + (size_t)mat * 262144; }
  else if (mat < 8) { src = Wg + (size_t)(mat - 4) * 262144; dst = Wgp + (size_t)(mat - 4) * 262144; }
  else              { src = (mat == 8 ? W1c : (mat == 9 ? W2c : Wgc));
                      dst = Cp + (size_t)(mat - 8) * 262144; }
  dst += (size_t)r * 8;
  int lane = r & 63;
  int n, k0;
  if (mat == 8 || mat == 9) {   // slab layout for ctx phases A/B
    int nb = r >> 12, kk = (r >> 8) & 15, ntg = (r >> 6) & 3;
    n  = nb * 64 + ntg * 16 + (lane & 15);
    k0 = kk * 32 + (lane >> 4) * 8;
  } else {                      // chunk layout for phase C / vsn
    int nt = (r >> 6) & 31, kk = (r >> 11) & 15;
    n  = nt * 16 + (lane & 15);
    k0 = kk * 32 + (lane >> 4) * 8;
  }
  short8 pk;
  #pragma unroll
  for (int j = 0; j < 8; ++j) pk[j] = (short)f2bf(src[(size_t)(k0 + j) * H + n]);
  *(short8*)dst = pk;
}

// ======================= 4-wave slab GEMM (phases A/B) =======================
__device__ __forceinline__ void slab_kloop(const TileCtx& c, const u16* Wslab,
                                           u16* sA, u16* sB0, u16* sB1,
                                           f32x4 acc[4]) {
  #pragma unroll 1
  for (int kk = 0; kk < 16; ++kk) {
    if (kk < 15)
      glld16(Wslab + (kk + 1) * 2048 + c.tid * 8,
             (((kk + 1) & 1) ? sB1 : sB0) + c.tid * 8);
    const u16* bp = ((kk & 1) ? sB1 : sB0) + c.wid * 512 + c.lane * 8;
    short8 bb = *(const short8*)(bp);
    const int kq = kk * 4 + c.quad;
    const int s0 = (kq ^ (c.col & 7)) * 8;
    short8 a0 = *(const short8*)&sA[(     c.col) * 512 + s0];
    short8 a1 = *(const short8*)&sA[(16 + c.col) * 512 + s0];
    short8 a2 = *(const short8*)&sA[(32 + c.col) * 512 + s0];
    short8 a3 = *(const short8*)&sA[(48 + c.col) * 512 + s0];
    acc[0] = MFMA16(a0, bb, acc[0]);
    acc[1] = MFMA16(a1, bb, acc[1]);
    acc[2] = MFMA16(a2, bb, acc[2]);
    acc[3] = MFMA16(a3, bb, acc[3]);
    __syncthreads();
  }
}

// ---------------- ctx_fused: g1 | gridbar | g2 | gridbar | g3-wide ----------
__global__ __launch_bounds__(256)
void ctx_fused(const float* __restrict__ in, const u16* __restrict__ Cp,
               const float* __restrict__ b1c, const float* __restrict__ b2c,
               const float* __restrict__ bgc,
               const float* __restrict__ gamma_c, const float* __restrict__ beta_c,
               const float* __restrict__ Wsel, const float* __restrict__ bsel,
               u16* __restrict__ x1g, u16* __restrict__ xg,
               float* __restrict__ sel_ws, float* __restrict__ selw_out,
               u32* __restrict__ bar)
{
  __shared__ __align__(16) u16 smem[49152];   // 96KB
  TileCtx c;
  c.tid = threadIdx.x; c.wid = c.tid >> 6; c.lane = c.tid & 63;
  c.quad = c.lane >> 4; c.col = c.lane & 15;
  const int blk = blockIdx.x;
  const int mb = blk >> 3, nb = blk & 7;
  const int m0 = mb * 64;

  // ======== phase A: x1 = elu(flat @ W1c + b1c) -> x1g ========
  {
    u16* const sA  = smem;
    u16* const sB0 = smem + 32768;
    u16* const sB1 = smem + 34816;
    const u16* Wslab = Cp + (size_t)nb * 32768;   // W1c slab
    glld16(Wslab + c.tid * 8, sB0 + c.tid * 8);   // chunk0
    {
      const int m = c.tid >> 2;
      const int kb = (c.tid & 3) * 128;
      const float* rowp = in + (size_t)(m0 + m) * H;
      #pragma unroll
      for (int gg = 0; gg < 16; ++gg) {
        const int ge = (gg + (c.tid & 3) * 4) & 15;
        const int k = kb + ge * 8;
        float4 v0 = *(const float4*)&rowp[k];
        float4 v1 = *(const float4*)&rowp[k + 4];
        u32x4 pk4;
        pk4.x = cvtpk(v0.x, v0.y); pk4.y = cvtpk(v0.z, v0.w);
        pk4.z = cvtpk(v1.x, v1.y); pk4.w = cvtpk(v1.z, v1.w);
        const int grp = (k >> 3) ^ (m & 7);
        *(u32x4*)&sA[m * 512 + grp * 8] = pk4;
      }
    }
    __syncthreads();
    f32x4 acc[4];
    #pragma unroll
    for (int mt = 0; mt < 4; ++mt) acc[mt] = (f32x4){0,0,0,0};
    slab_kloop(c, Wslab, sA, sB0, sB1, acc);
    const int n = nb * 64 + c.wid * 16 + c.col;
    const float bv = b1c[n];
    #pragma unroll
    for (int mt = 0; mt < 4; ++mt)
      #pragma unroll
      for (int reg = 0; reg < 4; ++reg) {
        const int m = m0 + mt * 16 + c.quad * 4 + reg;
        x1g[(size_t)m * H + n] = f2bf(elu_f(acc[mt][reg] + bv));
      }
  }
  gridbar(bar + 0, 32);

  // ======== phase B: x = x1 @ W2c + b2c -> xg ========
  {
    u16* const sA  = smem;
    u16* const sB0 = smem + 32768;
    u16* const sB1 = smem + 34816;
    const u16* Wslab = Cp + 262144 + (size_t)nb * 32768;   // W2c slab
    glld16(Wslab + c.tid * 8, sB0 + c.tid * 8);
    {
      const int m = c.tid >> 2;
      const int kb = (c.tid & 3) * 128;
      const u16* rowp = x1g + (size_t)(m0 + m) * H;
      #pragma unroll
      for (int gg = 0; gg < 16; ++gg) {
        const int ge = (gg + (c.tid & 3) * 4) & 15;
        const int k = kb + ge * 8;
        short8 w = *(const short8*)&rowp[k];
        const int grp = (k >> 3) ^ (m & 7);
        *(short8*)&sA[m * 512 + grp * 8] = w;
      }
    }
    __syncthreads();
    f32x4 acc[4];
    #pragma unroll
    for (int mt = 0; mt < 4; ++mt) acc[mt] = (f32x4){0,0,0,0};
    slab_kloop(c, Wslab, sA, sB0, sB1, acc);
    const int n = nb * 64 + c.wid * 16 + c.col;
    const float bv = b2c[n];
    #pragma unroll
    for (int mt = 0; mt < 4; ++mt)
      #pragma unroll
      for (int reg = 0; reg < 4; ++reg) {
        const int m = m0 + mt * 16 + c.quad * 4 + reg;
        xg[(size_t)m * H + n] = f2bf(acc[mt][reg] + bv);
      }
  }
  gridbar(bar + 1, 32);
  if (blk >= 8) return;

  // ======== phase C (blocks 0..7): 32 rows, gpre = x@Wgc; gate+LN+softmax ====
  {
    u16* const sA  = smem;              // [32][512] swizzled, 32KB
    u16* const sB0 = smem + 16384;      // 32KB chunk
    u16* const sB1 = smem + 32768;      // 32KB chunk
    float* const sRedF = (float*)sB0;   // LN partials (sB0 free after kloop)
    float* const sZp  = sRedF + 1024;   // [32][4][4] sel partials
    float* const sZf  = sRedF + 1792;   // [32][4] logits
    float* const sSel = sRedF + 1952;   // [32][4] softmax
    const int b0 = blk * 32;
    const u16* Wgcp = Cp + 524288;      // chunk layout

    #pragma unroll
    for (int i = 0; i < 8; ++i)         // stage chunk0 (32KB by 256 thr)
      glld16(Wgcp + (i * 256 + c.tid) * 8, sB0 + (i * 256 + c.tid) * 8);

    {   // A-fill: x bf16 -> swizzled sA (32 rows)
      const int m  = c.tid >> 3;        // 0..31
      const int kb = (c.tid & 7) * 64;
      const u16* rowp = xg + (size_t)(b0 + m) * H;
      #pragma unroll
      for (int gg = 0; gg < 8; ++gg) {
        const int ge = (gg + (c.tid & 7)) & 7;
        const int k = kb + ge * 8;
        short8 w = *(const short8*)&rowp[k];
        const int grp = (k >> 3) ^ (m & 7);
        *(short8*)&sA[m * 512 + grp * 8] = w;
      }
    }
    __syncthreads();

    f32x4 acc[2][8];
    #pragma unroll
    for (int mt = 0; mt < 2; ++mt)
      #pragma unroll
      for (int j = 0; j < 8; ++j) acc[mt][j] = (f32x4){0,0,0,0};

    #pragma unroll 1
    for (int kk = 0; kk < 16; ++kk) {
      if (kk < 15) {
        const u16* src = Wgcp + (kk + 1) * 16384;
        u16* dst = ((kk + 1) & 1) ? sB1 : sB0;
        #pragma unroll
        for (int i = 0; i < 8; ++i)
          glld16(src + (i * 256 + c.tid) * 8, dst + (i * 256 + c.tid) * 8);
      }
      const u16* bp = (kk & 1) ? sB1 : sB0;
      short8 bb[8];
      #pragma unroll
      for (int j = 0; j < 8; ++j)
        bb[j] = *(const short8*)(bp + ((c.wid * 8 + j) * 64 + c.lane) * 8);
      const int kq = kk * 4 + c.quad;
      const int s0 = (kq ^ (c.col & 7)) * 8;
      short8 a0 = *(const short8*)&sA[(     c.col) * 512 + s0];
      short8 a1 = *(const short8*)&sA[(16 + c.col) * 512 + s0];
      #pragma unroll
      for (int j = 0; j < 8; ++j) acc[0][j] = MFMA16(a0, bb[j], acc[0][j]);
      #pragma unroll
      for (int j = 0; j < 8; ++j) acc[1][j] = MFMA16(a1, bb[j], acc[1][j]);
      __syncthreads();
    }

    // gate: x from sA, skip from in (fp32)
    {
      float bv[8];
      #pragma unroll
      for (int j = 0; j < 8; ++j) bv[j] = bgc[c.wid * 128 + j * 16 + c.col];
      #pragma unroll
      for (int mt = 0; mt < 2; ++mt)
        #pragma unroll
        for (int j = 0; j < 8; ++j) {
          const int n = c.wid * 128 + j * 16 + c.col;
          #pragma unroll
          for (int reg = 0; reg < 4; ++reg) {
            const int m = mt * 16 + c.quad * 4 + reg;
            const float xv = bf2f(sA[sA_idx(m, n)]);
            const float fl = in[(size_t)(b0 + m) * H + n];
            const float gv = sigmoid_f(acc[mt][j][reg] + bv[j]);
            acc[mt][j][reg] = gv * xv + (1.0f - gv) * fl;
          }
        }
    }

    // LN partials (DPP) -> sRedF; finalize mu/rstd
    #pragma unroll
    for (int mt = 0; mt < 2; ++mt) {
      float rs[4], rq[4];
      #pragma unroll
      for (int reg = 0; reg < 4; ++reg) {
        rs[reg] = 0.f; rq[reg] = 0.f;
        #pragma unroll
        for (int j = 0; j < 8; ++j) {
          const float gt = acc[mt][j][reg];
          rs[reg] += gt; rq[reg] += gt * gt;
        }
        rs[reg] = red16(rs[reg]);
        rq[reg] = red16(rq[reg]);
      }
      if (c.col == 0) {
        #pragma unroll
        for (int reg = 0; reg < 4; ++reg) {
          const int m = mt * 16 + c.quad * 4 + reg;
          float2 sq; sq.x = rs[reg]; sq.y = rq[reg];
          *(float2*)&sRedF[m * 20 + c.wid * 2] = sq;
        }
      }
    }
    __syncthreads();
    if (c.tid < 32) {
      const int row = c.tid;
      float s = 0.f, q = 0.f;
      #pragma unroll
      for (int jj = 0; jj < 2; ++jj) {
        float4 v = *(float4*)&sRedF[row * 20 + jj * 4];
        s += v.x + v.z; q += v.y + v.w;
      }
      const float mu = s * (1.0f / H);
      const float rstd = rsqrtf(q * (1.0f / H) - mu * mu + 1e-3f);
      float2 mr; mr.x = mu; mr.y = rstd;
      *(float2*)&sRedF[640 + row * 2] = mr;
    }
    __syncthreads();

    // ctx (regs) + sel partials
    {
      float gm[8], bt[8]; float4 ws4[8];
      #pragma unroll
      for (int j = 0; j < 8; ++j) {
        const int n = c.wid * 128 + j * 16 + c.col;
        gm[j] = gamma_c[n]; bt[j] = beta_c[n];
        ws4[j] = *(const float4*)&Wsel[n * NF];
      }
      #pragma unroll
      for (int mt = 0; mt < 2; ++mt)
        #pragma unroll
        for (int reg = 0; reg < 4; ++reg) {
          const int m = mt * 16 + c.quad * 4 + reg;
          float2 mr = *(float2*)&sRedF[640 + m * 2];
          float zp[4] = {0.f, 0.f, 0.f, 0.f};
          #pragma unroll
          for (int j = 0; j < 8; ++j) {
            const float ctxv = gm[j] * ((acc[mt][j][reg] - mr.x) * mr.y) + bt[j];
            zp[0] = fmaf(ctxv, ws4[j].x, zp[0]);
            zp[1] = fmaf(ctxv, ws4[j].y, zp[1]);
            zp[2] = fmaf(ctxv, ws4[j].z, zp[2]);
            zp[3] = fmaf(ctxv, ws4[j].w, zp[3]);
          }
          #pragma unroll
          for (int f = 0; f < 4; ++f) zp[f] = red16(zp[f]);
          if (c.col == 0) {
            #pragma unroll
            for (int f = 0; f < 4; ++f) sZp[(m * 4 + c.wid) * 4 + f] = zp[f];
          }
        }
    }
    __syncthreads();
    if (c.tid < 128) {
      const int m = c.tid >> 2, f = c.tid & 3;
      float z = bsel[f];
      #pragma unroll
      for (int w = 0; w < 4; ++w) z += sZp[(m * 4 + w) * 4 + f];
      sZf[m * 4 + f] = z;
    }
    __syncthreads();
    if (c.tid < 32) {
      const int m = c.tid;
      float z0 = sZf[m*4], z1 = sZf[m*4+1], z2 = sZf[m*4+2], z3 = sZf[m*4+3];
      float mx = fmaxf(fmaxf(z0, z1), fmaxf(z2, z3));
      float e0 = __expf(z0-mx), e1 = __expf(z1-mx), e2 = __expf(z2-mx), e3 = __expf(z3-mx);
      float inv = __builtin_amdgcn_rcpf(e0 + e1 + e2 + e3);
      sSel[m*4]   = e0*inv; sSel[m*4+1] = e1*inv;
      sSel[m*4+2] = e2*inv; sSel[m*4+3] = e3*inv;
      sel_ws[(b0+m)*NF]   = e0*inv; sel_ws[(b0+m)*NF+1] = e1*inv;
      sel_ws[(b0+m)*NF+2] = e2*inv; sel_ws[(b0+m)*NF+3] = e3*inv;
    }
    __syncthreads();
    {
      const int m = c.tid >> 3;           // 0..31
      const int jb = (c.tid & 7) * 64;
      float4 v; v.x = sSel[m*4]; v.y = sSel[m*4+1]; v.z = sSel[m*4+2]; v.w = sSel[m*4+3];
      #pragma unroll
      for (int j = 0; j < 16; ++j)
        *(float4*)&selw_out[(size_t)(b0 + m) * H + jb + j * 4] = v;
    }
  }
}

// ======================= vsn machinery: B-in-registers k-loop =======================

// one K=32 step: 4 A ds_read_b128 + 16 MFMA with reg-resident B
__device__ __forceinline__ void mfma_step(const TileCtx& c, const u16* sAsrc,
                                          int kk, const short8 bb[4],
                                          f32x4 acc[4][4]) {
  const int kq = kk * 4 + c.quad;
  const int s0 = (kq ^ (c.col & 7)) * 8;
  __builtin_amdgcn_s_setprio(1);
  #pragma unroll
  for (int mt = 0; mt < 4; ++mt) {
    short8 a = *(const short8*)&sAsrc[(mt * 16 + c.col) * 512 + s0];
    #pragma unroll
    for (int nt = 0; nt < 4; ++nt)
      acc[mt][nt] = MFMA16(a, bb[nt], acc[mt][nt]);
  }
  __builtin_amdgcn_s_setprio(0);
}

// B fully in registers; double-buffered, unroll-2, barrier-free.
// b0 in: chunk0 of Wp (preloaded). b0 out: chunk0 of Wnext (tail prefetch;
// barrier drains make the loads land, reg values persist across barriers).
__device__ __forceinline__ void gemm_kloop_reg(const TileCtx& c, const u16* Wp,
                                               const u16* Wnext, const u16* sAsrc,
                                               short8 b0[4], f32x4 acc[4][4]) {
  const int off = c.wid * 2048 + c.lane * 8;   // wave-private contiguous slice
  short8 b1[4];
  #pragma unroll 1
  for (int kk = 0; kk < 16; kk += 2) {
    const u16* s1 = Wp + (kk + 1) * 16384 + off;
    #pragma unroll
    for (int nt = 0; nt < 4; ++nt) b1[nt] = *(const short8*)(s1 + nt * 512);
    mfma_step(c, sAsrc, kk, b0, acc);
    const u16* s2 = (kk < 14) ? (Wp + (kk + 2) * 16384 + off) : (Wnext + off);
    #pragma unroll
    for (int nt = 0; nt < 4; ++nt) b0[nt] = *(const short8*)(s2 + nt * 512);
    mfma_step(c, sAsrc, kk + 1, b1, acc);
  }
}

// store one C-layout value-pair set into a swizzled [64][512] tile.
__device__ __forceinline__ void store_x2_pair_n(const TileCtx& c, u16* dstT,
                                                int mt, int n, u32 o01, u32 o23) {
  const bool even = (c.lane & 1) == 0;
  const u32 send = even ? o23 : o01;
  const u32 recv = (u32)__builtin_amdgcn_update_dpp(0, (int)send, 0xB1, 0xF, 0xF, true);
  const u32 hi = even ? recv : o23;
  const u32 lo = even ? o01 : recv;
  const u32 dlo = __builtin_amdgcn_perm(hi, lo, 0x05040100u);
  const u32 dhi = __builtin_amdgcn_perm(hi, lo, 0x07060302u);
  const int np = n & ~1;
  const int mA = mt * 16 + c.quad * 4 + (even ? 0 : 2);
  const int iA = mA * 512 + ((((np >> 3) ^ (mA & 7)) << 3) + (np & 7));
  const int mB = mA + 1;
  const int iB = mB * 512 + ((((np >> 3) ^ (mB & 7)) << 3) + (np & 7));
  *(u32*)&dstT[iA] = dlo;
  *(u32*)&dstT[iB] = dhi;
}

// LN over 512 cols for 64 rows, 8-wave. Partials stride 20 floats.
__device__ __forceinline__ void ln_reduce8(const TileCtx& c, float* sRedF,
                                           f32x4 acc[4][4]) {
  #pragma unroll
  for (int mt = 0; mt < 4; ++mt) {
    float rs[4], rq[4];
    #pragma unroll
    for (int reg = 0; reg < 4; ++reg) {
      rs[reg] = 0.f; rq[reg] = 0.f;
      #pragma unroll
      for (int nt = 0; nt < 4; ++nt) {
        const float gt = acc[mt][nt][reg];
        rs[reg] += gt; rq[reg] += gt * gt;
      }
      rs[reg] = red16(rs[reg]);
      rq[reg] = red16(rq[reg]);
    }
    if (c.col == 0) {
      #pragma unroll
      for (int reg = 0; reg < 4; ++reg) {
        const int m = mt * 16 + c.quad * 4 + reg;
        float2 sq; sq.x = rs[reg]; sq.y = rq[reg];
        *(float2*)&sRedF[m * 20 + c.wid * 2] = sq;
      }
    }
  }
  __syncthreads();
  if (c.tid < 64) {
    const int row = c.tid;
    float s = 0.f, q = 0.f;
    #pragma unroll
    for (int jj = 0; jj < 4; ++jj) {
      float4 v = *(float4*)&sRedF[row * 20 + jj * 4];
      s += v.x + v.z; q += v.y + v.w;
    }
    const float mu = s * (1.0f / H);
    const float rstd = rsqrtf(q * (1.0f / H) - mu * mu + 1e-3f);
    float2 mr; mr.x = mu; mr.y = rstd;
    *(float2*)&sRedF[1280 + row * 2] = mr;
  }
  __syncthreads();
}

// ---------------- vsn_mfma: per-variable GRNs + weighted selection ----------------
__global__ __launch_bounds__(512, 2)
void vsn_mfma(const float* __restrict__ in,     // [MTOT, F]
              const float* __restrict__ w1, const float* __restrict__ b1,
              const float* __restrict__ b2, const float* __restrict__ bg,
              const float* __restrict__ gamma, const float* __restrict__ beta,
              const u16* __restrict__ W2p, const u16* __restrict__ Wgp,
              const float* __restrict__ sel_ws,  // [B, F]
              float* __restrict__ out)           // [MTOT, H]
{
  __shared__ __align__(16) u16 smem[65536];
  u16* const sA = smem;               // [64][512] x1 swizzled (+ sRedF overlay)
  u16* const sX = smem + 32768;       // [64][512] x2 swizzled
  float* const sRedF = (float*)smem;  // LN partials overlay sA (dead after GEMM1)

  TileCtx c;
  c.tid = threadIdx.x; c.wid = c.tid >> 6; c.lane = c.tid & 63;
  c.quad = c.lane >> 4; c.col = c.lane & 15;
  const int row0 = blockIdx.x * 64;
  const int bidx = row0 >> 7;

  f32x4 outacc[4][4];
  #pragma unroll
  for (int mt = 0; mt < 4; ++mt)
    #pragma unroll
    for (int nt = 0; nt < 4; ++nt) outacc[mt][nt] = (f32x4){0,0,0,0};

  // preload f=0 GEMM1 chunk0 slice into regs (latency covered by A1)
  short8 b0[4];
  {
    const u16* s = W2p + c.wid * 2048 + c.lane * 8;
    #pragma unroll
    for (int nt = 0; nt < 4; ++nt) b0[nt] = *(const short8*)(s + nt * 512);
  }

  #pragma unroll 1
  for (int f = 0; f < NF; ++f) {
    const u16* W2f = W2p + (size_t)f * 262144;
    const u16* Wgf = Wgp + (size_t)f * 262144;
    const u16* W2n = W2p + (size_t)((f + 1) & 3) * 262144;  // wraps; last is dead

    // A1: sA[m][k] = bf16(elu(v[m]*w1[k] + b1[k])), rotated k-group order
    {
      const int m  = c.tid >> 3;
      const int kb = (c.tid & 7) * 64;
      const float v = in[(size_t)(row0 + m) * NF + f];
      const float* w1f = w1 + f * H;
      const float* b1f = b1 + f * H;
      #pragma unroll
      for (int gg = 0; gg < 8; ++gg) {
        const int ge = (gg + (c.tid & 7)) & 7;
        const int k = kb + ge * 8;
        float4 wv0 = *(const float4*)&w1f[k];
        float4 wv1 = *(const float4*)&w1f[k + 4];
        float4 bv0 = *(const float4*)&b1f[k];
        float4 bv1 = *(const float4*)&b1f[k + 4];
        u32x4 pk4;
        pk4.x = cvtpk(elu_f(fmaf(v, wv0.x, bv0.x)), elu_f(fmaf(v, wv0.y, bv0.y)));
        pk4.y = cvtpk(elu_f(fmaf(v, wv0.z, bv0.z)), elu_f(fmaf(v, wv0.w, bv0.w)));
        pk4.z = cvtpk(elu_f(fmaf(v, wv1.x, bv1.x)), elu_f(fmaf(v, wv1.y, bv1.y)));
        pk4.w = cvtpk(elu_f(fmaf(v, wv1.z, bv1.z)), elu_f(fmaf(v, wv1.w, bv1.w)));
        const int grp = (k >> 3) ^ (m & 7);
        *(u32x4*)&sA[m * 512 + grp * 8] = pk4;
      }
    }
    __syncthreads();   // A1 visible; pending reg-loads drained (values live)

    f32x4 acc[4][4];
    #pragma unroll
    for (int mt = 0; mt < 4; ++mt)
      #pragma unroll
      for (int nt = 0; nt < 4; ++nt) acc[mt][nt] = (f32x4){0,0,0,0};

    // GEMM1: reads sA (x1), B in regs; tail loads Wgf chunk0 into b0
    gemm_kloop_reg(c, W2f, Wgf, sA, b0, acc);

    // epilogue1: x2 = acc + b2 -> sX (swizzled); no sA hazard, no barrier yet
    {
      float bv[4];
      #pragma unroll
      for (int nt = 0; nt < 4; ++nt) bv[nt] = b2[f * H + c.wid * 64 + nt * 16 + c.col];
      #pragma unroll
      for (int mt = 0; mt < 4; ++mt)
        #pragma unroll
        for (int nt = 0; nt < 4; ++nt) {
          const u32 o01 = cvtpk(acc[mt][nt][0] + bv[nt], acc[mt][nt][1] + bv[nt]);
          const u32 o23 = cvtpk(acc[mt][nt][2] + bv[nt], acc[mt][nt][3] + bv[nt]);
          store_x2_pair_n(c, sX, mt, c.wid * 64 + nt * 16 + c.col, o01, o23);
        }
    }
    __syncthreads();   // x2 in sX visible to all waves (also: GEMM1 sA reads done)

    // GEMM2: reads sX (x2), B in regs; tail loads next f's W2 chunk0 into b0
    #pragma unroll
    for (int mt = 0; mt < 4; ++mt)
      #pragma unroll
      for (int nt = 0; nt < 4; ++nt) acc[mt][nt] = (f32x4){0,0,0,0};
    gemm_kloop_reg(c, Wgf, W2n, sX, b0, acc);

    // gate (x2 re-read from sX) + LN + weighted accumulate
    {
      const float selw = sel_ws[bidx * NF + f];
      float bv[4];
      #pragma unroll
      for (int nt = 0; nt < 4; ++nt) bv[nt] = bg[f * H + c.wid * 64 + nt * 16 + c.col];
      #pragma unroll
      for (int mt = 0; mt < 4; ++mt) {
        float vr[4];
        #pragma unroll
        for (int reg = 0; reg < 4; ++reg)
          vr[reg] = in[(size_t)(row0 + mt * 16 + c.quad * 4 + reg) * NF + f];
        #pragma unroll
        for (int nt = 0; nt < 4; ++nt) {
          const int n = c.wid * 64 + nt * 16 + c.col;
          #pragma unroll
          for (int reg = 0; reg < 4; ++reg) {
            const int m = mt * 16 + c.quad * 4 + reg;
            const float x2v = bf2f(sX[sA_idx(m, n)]);
            const float gv = sigmoid_f(acc[mt][nt][reg] + bv[nt]);
            acc[mt][nt][reg] = gv * x2v + (1.0f - gv) * vr[reg];
          }
        }
      }
      // sRedF overlays sA: all sA (x1) reads ended at the epilogue barrier.
      ln_reduce8(c, sRedF, acc);
      float gm[4], bt[4];
      #pragma unroll
      for (int nt = 0; nt < 4; ++nt) {
        const int n = f * H + c.wid * 64 + nt * 16 + c.col;
        gm[nt] = gamma[n]; bt[nt] = beta[n];
      }
      #pragma unroll
      for (int mt = 0; mt < 4; ++mt)
        #pragma unroll
        for (int reg = 0; reg < 4; ++reg) {
          const int m = mt * 16 + c.quad * 4 + reg;
          float2 mr = *(float2*)&sRedF[1280 + m * 2];
          #pragma unroll
          for (int nt = 0; nt < 4; ++nt) {
            const float tv = gm[nt] * ((acc[mt][nt][reg] - mr.x) * mr.y) + bt[nt];
            outacc[mt][nt][reg] = fmaf(selw, tv, outacc[mt][nt][reg]);
          }
        }
      __syncthreads();   // sRedF/sX reads done before next f's sA/sX writes
    }
  }

  // store selected [MTOT, H]
  #pragma unroll
  for (int mt = 0; mt < 4; ++mt)
    #pragma unroll
    for (int reg = 0; reg < 4; ++reg) {
      const int m = row0 + mt * 16 + c.quad * 4 + reg;
      #pragma unroll
      for (int nt = 0; nt < 4; ++nt)
        out[(size_t)m * H + c.wid * 64 + nt * 16 + c.col] = outacc[mt][nt][reg];
    }
}

extern "C" void kernel_launch(void* const* d_in, const int* in_sizes, int n_in,
                              void* d_out, int out_size, void* d_ws, size_t ws_size,
                              hipStream_t stream) {
  const float* in_     = (const float*)d_in[0];
  const float* W1c     = (const float*)d_in[1];
  const float* b1c     = (const float*)d_in[2];
  const float* W2c     = (const float*)d_in[3];
  const float* b2c     = (const float*)d_in[4];
  const float* Wgc     = (const float*)d_in[5];
  const float* bgc     = (const float*)d_in[6];
  const float* gamma_c = (const float*)d_in[7];
  const float* beta_c  = (const float*)d_in[8];
  const float* Wsel    = (const float*)d_in[9];
  const float* bsel    = (const float*)d_in[10];
  const float* w1      = (const float*)d_in[11];
  const float* b1v     = (const float*)d_in[12];
  const float* W2      = (const float*)d_in[13];
  const float* b2v     = (const float*)d_in[14];
  const float* Wg      = (const float*)d_in[15];
  const float* bgv     = (const float*)d_in[16];
  const float* gma     = (const float*)d_in[17];
  const float* bta     = (const float*)d_in[18];

  float* out_sel = (float*)d_out;                      // [MTOT, H]
  float* out_w   = (float*)d_out + (size_t)MTOT * H;   // [B, T, 1, F]

  float* sel_ws = (float*)d_ws;                        // 4 KB
  u16*   W2p    = (u16*)((char*)d_ws + 4096);          // 2 MB
  u16*   Wgp    = W2p + (size_t)NF * H * H;            // 2 MB
  u16*   Cp     = Wgp + (size_t)NF * H * H;            // 1.5 MB (W1c|W2c|Wgc)
  u16*   x1g    = Cp + 3 * 262144;                     // 256 KB bf16 [256][512]
  u16*   xg     = x1g + 131072;                        // 256 KB bf16 [256][512]
  u32*   bar    = (u32*)(xg + 131072);                 // 2 barrier counters

  hipLaunchKernelGGL(pack_all, dim3(1408), dim3(256), 0, stream,
                     W2, Wg, W1c, W2c, Wgc, W2p, Wgp, Cp, bar);
  hipLaunchKernelGGL(ctx_fused, dim3(32), dim3(256), 0, stream,
                     in_, Cp, b1c, b2c, bgc, gamma_c, beta_c, Wsel, bsel,
                     x1g, xg, sel_ws, out_w, bar);
  hipLaunchKernelGGL(vsn_mfma, dim3(MTOT / 64), dim3(512), 0, stream,
                     in_, w1, b1v, b2v, bgv, gma, bta, W2p, Wgp, sel_ws, out_sel);
}

// Round 12
// 351.439 us; speedup vs baseline: 1.4768x; 1.4768x over previous
//
#include <hip/hip_runtime.h>
#include <math.h>

// VariableSelectionNetwork — round 14.
// R13 (B-in-regs) spilled exactly as the pre-set falsifier predicted (WRITE
// 90->194MB): 32 live B-regs in the kloop blew the 128-arch cap. Lesson: at
// 2 waves/SIMD + 128 accum regs, NO new >=16-reg live range fits in the
// k-loop; B stays in LDS via R12's wave-private staging.
// This round: vsn reverted to R12-EXACT (233us, all counter predictions
// verified). Risk budget spent on ctx phase C instead: was 8 of 32 blocks
// x 32 rows -> now 16 blocks x 16 rows (acc[1][8]; Wgc is L2-resident so
// per-block weight re-reads are free). Phases A/B + gridbar + pack_all
// byte-identical.

#define H 512
#define NF 4
#define MTOT 32768

typedef unsigned short u16;
typedef unsigned int u32;
typedef __attribute__((ext_vector_type(8))) short short8;   // 8 bf16 = 4 VGPRs
typedef __attribute__((ext_vector_type(4))) float f32x4;    // MFMA C/D
typedef __attribute__((ext_vector_type(4))) u32 u32x4;      // packed bf16 x8

__device__ __forceinline__ u16 f2bf(float x) {
  union { float f; u32 u; } v; v.f = x;
  return (u16)((v.u + 0x7fffu + ((v.u >> 16) & 1u)) >> 16);  // RNE
}
__device__ __forceinline__ float bf2f(u32 h16) {
  union { u32 u; float f; } v; v.u = h16 << 16;
  return v.f;
}
__device__ __forceinline__ float elu_f(float x) {
  return x > 0.0f ? x : (__expf(x) - 1.0f);
}
__device__ __forceinline__ float sigmoid_f(float x) {
  return __builtin_amdgcn_rcpf(1.0f + __expf(-x));
}
// packed 2x bf16 (lo->[15:0], hi->[31:16]), RNE — matches f2bf
__device__ __forceinline__ u32 cvtpk(float lo, float hi) {
  u32 r;
  asm("v_cvt_pk_bf16_f32 %0, %1, %2" : "=v"(r) : "v"(lo), "v"(hi));
  return r;
}
// butterfly-add over 16-lane groups via DPP (VALU pipe, no LDS)
template <int CTRL>
__device__ __forceinline__ float dppadd(float v) {
  int t = __builtin_amdgcn_update_dpp(0, __float_as_int(v), CTRL, 0xF, 0xF, true);
  return v + __int_as_float(t);
}
__device__ __forceinline__ float red16(float v) {
  v = dppadd<0xB1>(v);    // xor1
  v = dppadd<0x4E>(v);    // xor2
  v = dppadd<0x141>(v);   // row_half_mirror
  v = dppadd<0x140>(v);   // row_mirror
  return v;
}

// async global->LDS, 16B per lane; LDS dest = wave-uniform base + lane*16.
__device__ __forceinline__ void glld16(const void* g, void* l) {
  __builtin_amdgcn_global_load_lds(
      (const __attribute__((address_space(1))) u32*)(unsigned long long)(uintptr_t)g,
      (__attribute__((address_space(3))) u32*)(u32)(uintptr_t)l, 16, 0, 0);
}

#define MFMA16(a, b, c) __builtin_amdgcn_mfma_f32_16x16x32_bf16((a), (b), (c), 0, 0, 0)

// x value stored in swizzled tile at logical (m,n):
__device__ __forceinline__ int sA_idx(int m, int n) {
  return m * 512 + ((((n >> 3) ^ (m & 7)) << 3) + (n & 7));
}

// device-scope grid barrier: all blocks arrive, then proceed. cnt pre-zeroed.
__device__ __forceinline__ void gridbar(u32* cnt, u32 target) {
  __syncthreads();
  __threadfence();
  if (threadIdx.x == 0) {
    __hip_atomic_fetch_add(cnt, 1u, __ATOMIC_RELEASE, __HIP_MEMORY_SCOPE_AGENT);
    while (__hip_atomic_load(cnt, __ATOMIC_ACQUIRE, __HIP_MEMORY_SCOPE_AGENT) < target)
      __builtin_amdgcn_s_sleep(8);
  }
  __syncthreads();
  __threadfence();
}

struct TileCtx {
  int tid, wid, lane, quad, col;
};

// ---------------- pack_all: all 11 matrices + barrier-counter reset. -------
__global__ __launch_bounds__(256)
void pack_all(const float* __restrict__ W2, const float* __restrict__ Wg,
              const float* __restrict__ W1c, const float* __restrict__ W2c,
              const float* __restrict__ Wgc,
              u16* __restrict__ W2p, u16* __restrict__ Wgp, u16* __restrict__ Cp,
              u32* __restrict__ bar) {
  int g = blockIdx.x * 256 + threadIdx.x;       // 0 .. 11*32768-1
  if (g == 0) { bar[0] = 0; bar[1] = 0; }
  int r = g & 32767; int mat = g >> 15;
  if (mat >= 11) return;
  const float* src; u16* dst;
  if (mat < 4)      { src = W2 + (size_t)mat * 262144;       dst = W2p + (size_t)mat * 262144; }
  else if (mat < 8) { src = Wg + (size_t)(mat - 4) * 262144; dst = Wgp + (size_t)(mat - 4) * 262144; }
  else              { src = (mat == 8 ? W1c : (mat == 9 ? W2c : Wgc));
                      dst = Cp + (size_t)(mat - 8) * 262144; }
  dst += (size_t)r * 8;
  int lane = r & 63;
  int n, k0;
  if (mat == 8 || mat == 9) {   // slab layout for ctx phases A/B
    int nb = r >> 12, kk = (r >> 8) & 15, ntg = (r >> 6) & 3;
    n  = nb * 64 + ntg * 16 + (lane & 15);
    k0 = kk * 32 + (lane >> 4) * 8;
  } else {                      // chunk layout for phase C / vsn
    int nt = (r >> 6) & 31, kk = (r >> 11) & 15;
    n  = nt * 16 + (lane & 15);
    k0 = kk * 32 + (lane >> 4) * 8;
  }
  short8 pk;
  #pragma unroll
  for (int j = 0; j < 8; ++j) pk[j] = (short)f2bf(src[(size_t)(k0 + j) * H + n]);
  *(short8*)dst = pk;
}

// ======================= 4-wave slab GEMM (phases A/B) =======================
__device__ __forceinline__ void slab_kloop(const TileCtx& c, const u16* Wslab,
                                           u16* sA, u16* sB0, u16* sB1,
                                           f32x4 acc[4]) {
  #pragma unroll 1
  for (int kk = 0; kk < 16; ++kk) {
    if (kk < 15)
      glld16(Wslab + (kk + 1) * 2048 + c.tid * 8,
             (((kk + 1) & 1) ? sB1 : sB0) + c.tid * 8);
    const u16* bp = ((kk & 1) ? sB1 : sB0) + c.wid * 512 + c.lane * 8;
    short8 bb = *(const short8*)(bp);
    const int kq = kk * 4 + c.quad;
    const int s0 = (kq ^ (c.col & 7)) * 8;
    short8 a0 = *(const short8*)&sA[(     c.col) * 512 + s0];
    short8 a1 = *(const short8*)&sA[(16 + c.col) * 512 + s0];
    short8 a2 = *(const short8*)&sA[(32 + c.col) * 512 + s0];
    short8 a3 = *(const short8*)&sA[(48 + c.col) * 512 + s0];
    acc[0] = MFMA16(a0, bb, acc[0]);
    acc[1] = MFMA16(a1, bb, acc[1]);
    acc[2] = MFMA16(a2, bb, acc[2]);
    acc[3] = MFMA16(a3, bb, acc[3]);
    __syncthreads();
  }
}

// ---------------- ctx_fused: g1 | gridbar | g2 | gridbar | g3-wide ----------
// grid 32 x 256 thr. Phases A/B: (mb,nb) 64x64 slab GEMMs. Phase C: blocks
// 0..15, 16 rows each, full-width K=512 GEMM + gate + LN + softmax + selw.
__global__ __launch_bounds__(256)
void ctx_fused(const float* __restrict__ in, const u16* __restrict__ Cp,
               const float* __restrict__ b1c, const float* __restrict__ b2c,
               const float* __restrict__ bgc,
               const float* __restrict__ gamma_c, const float* __restrict__ beta_c,
               const float* __restrict__ Wsel, const float* __restrict__ bsel,
               u16* __restrict__ x1g, u16* __restrict__ xg,
               float* __restrict__ sel_ws, float* __restrict__ selw_out,
               u32* __restrict__ bar)
{
  __shared__ __align__(16) u16 smem[49152];   // 96KB
  TileCtx c;
  c.tid = threadIdx.x; c.wid = c.tid >> 6; c.lane = c.tid & 63;
  c.quad = c.lane >> 4; c.col = c.lane & 15;
  const int blk = blockIdx.x;
  const int mb = blk >> 3, nb = blk & 7;
  const int m0 = mb * 64;

  // ======== phase A: x1 = elu(flat @ W1c + b1c) -> x1g ========
  {
    u16* const sA  = smem;
    u16* const sB0 = smem + 32768;
    u16* const sB1 = smem + 34816;
    const u16* Wslab = Cp + (size_t)nb * 32768;   // W1c slab
    glld16(Wslab + c.tid * 8, sB0 + c.tid * 8);   // chunk0
    {
      const int m = c.tid >> 2;
      const int kb = (c.tid & 3) * 128;
      const float* rowp = in + (size_t)(m0 + m) * H;
      #pragma unroll
      for (int gg = 0; gg < 16; ++gg) {
        const int ge = (gg + (c.tid & 3) * 4) & 15;
        const int k = kb + ge * 8;
        float4 v0 = *(const float4*)&rowp[k];
        float4 v1 = *(const float4*)&rowp[k + 4];
        u32x4 pk4;
        pk4.x = cvtpk(v0.x, v0.y); pk4.y = cvtpk(v0.z, v0.w);
        pk4.z = cvtpk(v1.x, v1.y); pk4.w = cvtpk(v1.z, v1.w);
        const int grp = (k >> 3) ^ (m & 7);
        *(u32x4*)&sA[m * 512 + grp * 8] = pk4;
      }
    }
    __syncthreads();
    f32x4 acc[4];
    #pragma unroll
    for (int mt = 0; mt < 4; ++mt) acc[mt] = (f32x4){0,0,0,0};
    slab_kloop(c, Wslab, sA, sB0, sB1, acc);
    const int n = nb * 64 + c.wid * 16 + c.col;
    const float bv = b1c[n];
    #pragma unroll
    for (int mt = 0; mt < 4; ++mt)
      #pragma unroll
      for (int reg = 0; reg < 4; ++reg) {
        const int m = m0 + mt * 16 + c.quad * 4 + reg;
        x1g[(size_t)m * H + n] = f2bf(elu_f(acc[mt][reg] + bv));
      }
  }
  gridbar(bar + 0, 32);

  // ======== phase B: x = x1 @ W2c + b2c -> xg ========
  {
    u16* const sA  = smem;
    u16* const sB0 = smem + 32768;
    u16* const sB1 = smem + 34816;
    const u16* Wslab = Cp + 262144 + (size_t)nb * 32768;   // W2c slab
    glld16(Wslab + c.tid * 8, sB0 + c.tid * 8);
    {
      const int m = c.tid >> 2;
      const int kb = (c.tid & 3) * 128;
      const u16* rowp = x1g + (size_t)(m0 + m) * H;
      #pragma unroll
      for (int gg = 0; gg < 16; ++gg) {
        const int ge = (gg + (c.tid & 3) * 4) & 15;
        const int k = kb + ge * 8;
        short8 w = *(const short8*)&rowp[k];
        const int grp = (k >> 3) ^ (m & 7);
        *(short8*)&sA[m * 512 + grp * 8] = w;
      }
    }
    __syncthreads();
    f32x4 acc[4];
    #pragma unroll
    for (int mt = 0; mt < 4; ++mt) acc[mt] = (f32x4){0,0,0,0};
    slab_kloop(c, Wslab, sA, sB0, sB1, acc);
    const int n = nb * 64 + c.wid * 16 + c.col;
    const float bv = b2c[n];
    #pragma unroll
    for (int mt = 0; mt < 4; ++mt)
      #pragma unroll
      for (int reg = 0; reg < 4; ++reg) {
        const int m = m0 + mt * 16 + c.quad * 4 + reg;
        xg[(size_t)m * H + n] = f2bf(acc[mt][reg] + bv);
      }
  }
  gridbar(bar + 1, 32);
  if (blk >= 16) return;

  // ======== phase C (blocks 0..15): 16 rows, gpre = x@Wgc; gate+LN+softmax ====
  {
    u16* const sA  = smem;              // [16][512] swizzled, 16KB
    u16* const sB0 = smem + 8192;       // 32KB chunk
    u16* const sB1 = smem + 24576;      // 32KB chunk
    float* const sRedF = (float*)sB0;   // LN partials (sB0 free after kloop)
    float* const sZp  = sRedF + 1024;   // [16][4][4] sel partials
    float* const sZf  = sRedF + 1792;   // [16][4] logits
    float* const sSel = sRedF + 1952;   // [16][4] softmax
    const int b0 = blk * 16;
    const u16* Wgcp = Cp + 524288;      // chunk layout

    #pragma unroll
    for (int i = 0; i < 8; ++i)         // stage chunk0 (32KB by 256 thr)
      glld16(Wgcp + (i * 256 + c.tid) * 8, sB0 + (i * 256 + c.tid) * 8);

    {   // A-fill: x bf16 -> swizzled sA (16 rows)
      const int m  = c.tid >> 4;        // 0..15
      const int kb = (c.tid & 15) * 32;
      const u16* rowp = xg + (size_t)(b0 + m) * H;
      #pragma unroll
      for (int gg = 0; gg < 4; ++gg) {
        const int ge = (gg + (c.tid & 15)) & 3;
        const int k = kb + ge * 8;
        short8 w = *(const short8*)&rowp[k];
        const int grp = (k >> 3) ^ (m & 7);
        *(short8*)&sA[m * 512 + grp * 8] = w;
      }
    }
    __syncthreads();

    f32x4 acc8[8];
    #pragma unroll
    for (int j = 0; j < 8; ++j) acc8[j] = (f32x4){0,0,0,0};

    #pragma unroll 1
    for (int kk = 0; kk < 16; ++kk) {
      if (kk < 15) {
        const u16* src = Wgcp + (kk + 1) * 16384;
        u16* dst = ((kk + 1) & 1) ? sB1 : sB0;
        #pragma unroll
        for (int i = 0; i < 8; ++i)
          glld16(src + (i * 256 + c.tid) * 8, dst + (i * 256 + c.tid) * 8);
      }
      const u16* bp = (kk & 1) ? sB1 : sB0;
      short8 bb[8];
      #pragma unroll
      for (int j = 0; j < 8; ++j)
        bb[j] = *(const short8*)(bp + ((c.wid * 8 + j) * 64 + c.lane) * 8);
      const int kq = kk * 4 + c.quad;
      const int s0 = (kq ^ (c.col & 7)) * 8;
      short8 a0 = *(const short8*)&sA[c.col * 512 + s0];
      #pragma unroll
      for (int j = 0; j < 8; ++j) acc8[j] = MFMA16(a0, bb[j], acc8[j]);
      __syncthreads();
    }

    // gate: x from sA, skip from in (fp32)
    {
      float bv[8];
      #pragma unroll
      for (int j = 0; j < 8; ++j) bv[j] = bgc[c.wid * 128 + j * 16 + c.col];
      #pragma unroll
      for (int j = 0; j < 8; ++j) {
        const int n = c.wid * 128 + j * 16 + c.col;
        #pragma unroll
        for (int reg = 0; reg < 4; ++reg) {
          const int m = c.quad * 4 + reg;
          const float xv = bf2f(sA[sA_idx(m, n)]);
          const float fl = in[(size_t)(b0 + m) * H + n];
          const float gv = sigmoid_f(acc8[j][reg] + bv[j]);
          acc8[j][reg] = gv * xv + (1.0f - gv) * fl;
        }
      }
    }

    // LN partials (DPP) -> sRedF; finalize mu/rstd
    {
      float rs[4], rq[4];
      #pragma unroll
      for (int reg = 0; reg < 4; ++reg) {
        rs[reg] = 0.f; rq[reg] = 0.f;
        #pragma unroll
        for (int j = 0; j < 8; ++j) {
          const float gt = acc8[j][reg];
          rs[reg] += gt; rq[reg] += gt * gt;
        }
        rs[reg] = red16(rs[reg]);
        rq[reg] = red16(rq[reg]);
      }
      if (c.col == 0) {
        #pragma unroll
        for (int reg = 0; reg < 4; ++reg) {
          const int m = c.quad * 4 + reg;
          float2 sq; sq.x = rs[reg]; sq.y = rq[reg];
          *(float2*)&sRedF[m * 20 + c.wid * 2] = sq;
        }
      }
    }
    __syncthreads();
    if (c.tid < 16) {
      const int row = c.tid;
      float s = 0.f, q = 0.f;
      #pragma unroll
      for (int jj = 0; jj < 2; ++jj) {
        float4 v = *(float4*)&sRedF[row * 20 + jj * 4];
        s += v.x + v.z; q += v.y + v.w;
      }
      const float mu = s * (1.0f / H);
      const float rstd = rsqrtf(q * (1.0f / H) - mu * mu + 1e-3f);
      float2 mr; mr.x = mu; mr.y = rstd;
      *(float2*)&sRedF[640 + row * 2] = mr;
    }
    __syncthreads();

    // ctx (regs) + sel partials
    {
      float gm[8], bt[8]; float4 ws4[8];
      #pragma unroll
      for (int j = 0; j < 8; ++j) {
        const int n = c.wid * 128 + j * 16 + c.col;
        gm[j] = gamma_c[n]; bt[j] = beta_c[n];
        ws4[j] = *(const float4*)&Wsel[n * NF];
      }
      #pragma unroll
      for (int reg = 0; reg < 4; ++reg) {
        const int m = c.quad * 4 + reg;
        float2 mr = *(float2*)&sRedF[640 + m * 2];
        float zp[4] = {0.f, 0.f, 0.f, 0.f};
        #pragma unroll
        for (int j = 0; j < 8; ++j) {
          const float ctxv = gm[j] * ((acc8[j][reg] - mr.x) * mr.y) + bt[j];
          zp[0] = fmaf(ctxv, ws4[j].x, zp[0]);
          zp[1] = fmaf(ctxv, ws4[j].y, zp[1]);
          zp[2] = fmaf(ctxv, ws4[j].z, zp[2]);
          zp[3] = fmaf(ctxv, ws4[j].w, zp[3]);
        }
        #pragma unroll
        for (int f = 0; f < 4; ++f) zp[f] = red16(zp[f]);
        if (c.col == 0) {
          #pragma unroll
          for (int f = 0; f < 4; ++f) sZp[(m * 4 + c.wid) * 4 + f] = zp[f];
        }
      }
    }
    __syncthreads();
    if (c.tid < 64) {
      const int m = c.tid >> 2, f = c.tid & 3;
      float z = bsel[f];
      #pragma unroll
      for (int w = 0; w < 4; ++w) z += sZp[(m * 4 + w) * 4 + f];
      sZf[m * 4 + f] = z;
    }
    __syncthreads();
    if (c.tid < 16) {
      const int m = c.tid;
      float z0 = sZf[m*4], z1 = sZf[m*4+1], z2 = sZf[m*4+2], z3 = sZf[m*4+3];
      float mx = fmaxf(fmaxf(z0, z1), fmaxf(z2, z3));
      float e0 = __expf(z0-mx), e1 = __expf(z1-mx), e2 = __expf(z2-mx), e3 = __expf(z3-mx);
      float inv = __builtin_amdgcn_rcpf(e0 + e1 + e2 + e3);
      sSel[m*4]   = e0*inv; sSel[m*4+1] = e1*inv;
      sSel[m*4+2] = e2*inv; sSel[m*4+3] = e3*inv;
      sel_ws[(b0+m)*NF]   = e0*inv; sel_ws[(b0+m)*NF+1] = e1*inv;
      sel_ws[(b0+m)*NF+2] = e2*inv; sel_ws[(b0+m)*NF+3] = e3*inv;
    }
    __syncthreads();
    {
      const int m = c.tid >> 4;           // 0..15
      const int jb = (c.tid & 15) * 32;
      float4 v; v.x = sSel[m*4]; v.y = sSel[m*4+1]; v.z = sSel[m*4+2]; v.w = sSel[m*4+3];
      #pragma unroll
      for (int j = 0; j < 8; ++j)
        *(float4*)&selw_out[(size_t)(b0 + m) * H + jb + j * 4] = v;
    }
  }
}

// ======================= vsn machinery: wave-private barrier-free k-loop (R12-exact) =======================

// wave-private staging: wave wid's 4KB slice (cols wid*64..+63) of a 32KB chunk.
// Packed layout => slice is contiguous at chunk + wid*2048 (u16).
__device__ __forceinline__ void stage_slice(int wid, int lane, const u16* chunk, u16* dstbuf) {
  const u16* src = chunk + wid * 2048 + lane * 8;
  u16* dst = dstbuf + lane * 8;
  glld16(src,        dst);
  glld16(src + 512,  dst + 512);
  glld16(src + 1024, dst + 1024);
  glld16(src + 1536, dst + 1536);
}

// barrier-free K-loop: per-wave double-buffered B slices, per-wave vmcnt.
// Entry: chunk0 already in sBw buf0 (drained by a preceding __syncthreads).
__device__ __forceinline__ void gemm_kloop_nb(const TileCtx& c, const u16* Wp,
                                              const u16* sA, u16* sBw,
                                              f32x4 acc[4][4]) {
  #pragma unroll 1
  for (int kk = 0; kk < 16; ++kk) {
    if (kk < 15) {
      stage_slice(c.wid, c.lane, Wp + (kk + 1) * 16384, sBw + ((kk + 1) & 1) * 2048);
      asm volatile("s_waitcnt vmcnt(4)" ::: "memory");   // chunk kk's 4 landed (own wave)
    } else {
      asm volatile("s_waitcnt vmcnt(0)" ::: "memory");
    }
    __builtin_amdgcn_sched_barrier(0);
    const u16* bp = sBw + (kk & 1) * 2048 + c.lane * 8;
    short8 bb[4];
    #pragma unroll
    for (int nt = 0; nt < 4; ++nt) bb[nt] = *(const short8*)(bp + nt * 512);
    const int kq = kk * 4 + c.quad;
    const int s0 = (kq ^ (c.col & 7)) * 8;
    __builtin_amdgcn_s_setprio(1);
    #pragma unroll
    for (int mt = 0; mt < 4; ++mt) {
      short8 a = *(const short8*)&sA[(mt * 16 + c.col) * 512 + s0];
      #pragma unroll
      for (int nt = 0; nt < 4; ++nt)
        acc[mt][nt] = MFMA16(a, bb[nt], acc[mt][nt]);
    }
    __builtin_amdgcn_s_setprio(0);
  }
}

// store one C-layout value-pair set into sA[m][k] bf16 via lane-pair exchange.
__device__ __forceinline__ void store_x2_pair_n(const TileCtx& c, u16* sA,
                                                int mt, int n, u32 o01, u32 o23) {
  const bool even = (c.lane & 1) == 0;
  const u32 send = even ? o23 : o01;
  const u32 recv = (u32)__builtin_amdgcn_update_dpp(0, (int)send, 0xB1, 0xF, 0xF, true);
  const u32 hi = even ? recv : o23;
  const u32 lo = even ? o01 : recv;
  const u32 dlo = __builtin_amdgcn_perm(hi, lo, 0x05040100u);
  const u32 dhi = __builtin_amdgcn_perm(hi, lo, 0x07060302u);
  const int np = n & ~1;
  const int mA = mt * 16 + c.quad * 4 + (even ? 0 : 2);
  const int iA = mA * 512 + ((((np >> 3) ^ (mA & 7)) << 3) + (np & 7));
  const int mB = mA + 1;
  const int iB = mB * 512 + ((((np >> 3) ^ (mB & 7)) << 3) + (np & 7));
  *(u32*)&sA[iA] = dlo;
  *(u32*)&sA[iB] = dhi;
}

// LN over 512 cols for 64 rows, 8-wave. Partials stride 20 floats.
__device__ __forceinline__ void ln_reduce8(const TileCtx& c, float* sRedF,
                                           f32x4 acc[4][4]) {
  #pragma unroll
  for (int mt = 0; mt < 4; ++mt) {
    float rs[4], rq[4];
    #pragma unroll
    for (int reg = 0; reg < 4; ++reg) {
      rs[reg] = 0.f; rq[reg] = 0.f;
      #pragma unroll
      for (int nt = 0; nt < 4; ++nt) {
        const float gt = acc[mt][nt][reg];
        rs[reg] += gt; rq[reg] += gt * gt;
      }
      rs[reg] = red16(rs[reg]);
      rq[reg] = red16(rq[reg]);
    }
    if (c.col == 0) {
      #pragma unroll
      for (int reg = 0; reg < 4; ++reg) {
        const int m = mt * 16 + c.quad * 4 + reg;
        float2 sq; sq.x = rs[reg]; sq.y = rq[reg];
        *(float2*)&sRedF[m * 20 + c.wid * 2] = sq;
      }
    }
  }
  __syncthreads();
  if (c.tid < 64) {
    const int row = c.tid;
    float s = 0.f, q = 0.f;
    #pragma unroll
    for (int jj = 0; jj < 4; ++jj) {
      float4 v = *(float4*)&sRedF[row * 20 + jj * 4];
      s += v.x + v.z; q += v.y + v.w;
    }
    const float mu = s * (1.0f / H);
    const float rstd = rsqrtf(q * (1.0f / H) - mu * mu + 1e-3f);
    float2 mr; mr.x = mu; mr.y = rstd;
    *(float2*)&sRedF[1280 + row * 2] = mr;
  }
  __syncthreads();
}

// ---------------- vsn_mfma: per-variable GRNs + weighted selection ----------------
__global__ __launch_bounds__(512, 2)
void vsn_mfma(const float* __restrict__ in,     // [MTOT, F]
              const float* __restrict__ w1, const float* __restrict__ b1,
              const float* __restrict__ b2, const float* __restrict__ bg,
              const float* __restrict__ gamma, const float* __restrict__ beta,
              const u16* __restrict__ W2p, const u16* __restrict__ Wgp,
              const float* __restrict__ sel_ws,  // [B, F]
              float* __restrict__ out)           // [MTOT, H]
{
  __shared__ __align__(16) u16 smem[65536];
  u16* const sA  = smem;              // [64][512] bf16 XOR-swizzled, 64 KB
  u16* const sB  = smem + 32768;      // 8 waves x 8KB double-buffer slices
  float* const sRedF = (float*)smem;  // LN partials overlay sA (x2 in regs)

  TileCtx c;
  c.tid = threadIdx.x; c.wid = c.tid >> 6; c.lane = c.tid & 63;
  c.quad = c.lane >> 4; c.col = c.lane & 15;
  u16* const sBw = sB + c.wid * 4096;  // this wave's 8KB (2 x 2048 u16)
  const int row0 = blockIdx.x * 64;
  const int bidx = row0 >> 7;

  f32x4 outacc[4][4];
  #pragma unroll
  for (int mt = 0; mt < 4; ++mt)
    #pragma unroll
    for (int nt = 0; nt < 4; ++nt) outacc[mt][nt] = (f32x4){0,0,0,0};

  // stage f=0 GEMM1 chunk0 slice (overlapped by first A1 phase)
  stage_slice(c.wid, c.lane, W2p, sBw);

  #pragma unroll 1
  for (int f = 0; f < NF; ++f) {
    const u16* W2f = W2p + (size_t)f * 262144;
    const u16* Wgf = Wgp + (size_t)f * 262144;

    // A1: sA[m][k] = bf16(elu(v[m]*w1[k] + b1[k])), rotated k-group order
    {
      const int m  = c.tid >> 3;
      const int kb = (c.tid & 7) * 64;
      const float v = in[(size_t)(row0 + m) * NF + f];
      const float* w1f = w1 + f * H;
      const float* b1f = b1 + f * H;
      #pragma unroll
      for (int gg = 0; gg < 8; ++gg) {
        const int ge = (gg + (c.tid & 7)) & 7;
        const int k = kb + ge * 8;
        float4 wv0 = *(const float4*)&w1f[k];
        float4 wv1 = *(const float4*)&w1f[k + 4];
        float4 bv0 = *(const float4*)&b1f[k];
        float4 bv1 = *(const float4*)&b1f[k + 4];
        u32x4 pk4;
        pk4.x = cvtpk(elu_f(fmaf(v, wv0.x, bv0.x)), elu_f(fmaf(v, wv0.y, bv0.y)));
        pk4.y = cvtpk(elu_f(fmaf(v, wv0.z, bv0.z)), elu_f(fmaf(v, wv0.w, bv0.w)));
        pk4.z = cvtpk(elu_f(fmaf(v, wv1.x, bv1.x)), elu_f(fmaf(v, wv1.y, bv1.y)));
        pk4.w = cvtpk(elu_f(fmaf(v, wv1.z, bv1.z)), elu_f(fmaf(v, wv1.w, bv1.w)));
        const int grp = (k >> 3) ^ (m & 7);
        *(u32x4*)&sA[m * 512 + grp * 8] = pk4;
      }
    }
    __syncthreads();   // A1 visible; chunk0 slices drained (vmcnt 0)

    f32x4 acc[4][4];
    #pragma unroll
    for (int mt = 0; mt < 4; ++mt)
      #pragma unroll
      for (int nt = 0; nt < 4; ++nt) acc[mt][nt] = (f32x4){0,0,0,0};

    // GEMM1: barrier-free, per-wave staged
    gemm_kloop_nb(c, W2f, sA, sBw, acc);
    __syncthreads();   // all waves done reading sA (x1) before x2 overwrite

    // prefetch GEMM2 chunk0 slice (covered by epilogue; drained at next bar)
    stage_slice(c.wid, c.lane, Wgf, sBw);

    // epilogue1: x2 = acc + b2 -> packed regs + sA
    u32 x2p[4][4][2];
    {
      float bv[4];
      #pragma unroll
      for (int nt = 0; nt < 4; ++nt) bv[nt] = b2[f * H + c.wid * 64 + nt * 16 + c.col];
      #pragma unroll
      for (int mt = 0; mt < 4; ++mt)
        #pragma unroll
        for (int nt = 0; nt < 4; ++nt) {
          const u32 o01 = cvtpk(acc[mt][nt][0] + bv[nt], acc[mt][nt][1] + bv[nt]);
          const u32 o23 = cvtpk(acc[mt][nt][2] + bv[nt], acc[mt][nt][3] + bv[nt]);
          x2p[mt][nt][0] = o01; x2p[mt][nt][1] = o23;
          store_x2_pair_n(c, sA, mt, c.wid * 64 + nt * 16 + c.col, o01, o23);
        }
    }
    __syncthreads();   // x2 visible; chunk0 drained

    // GEMM2: barrier-free
    #pragma unroll
    for (int mt = 0; mt < 4; ++mt)
      #pragma unroll
      for (int nt = 0; nt < 4; ++nt) acc[mt][nt] = (f32x4){0,0,0,0};
    gemm_kloop_nb(c, Wgf, sA, sBw, acc);

    // gate (reg-only: acc, x2p, in, bv)
    {
      const float selw = sel_ws[bidx * NF + f];
      float bv[4];
      #pragma unroll
      for (int nt = 0; nt < 4; ++nt) bv[nt] = bg[f * H + c.wid * 64 + nt * 16 + c.col];
      #pragma unroll
      for (int mt = 0; mt < 4; ++mt) {
        float vr[4];
        #pragma unroll
        for (int reg = 0; reg < 4; ++reg)
          vr[reg] = in[(size_t)(row0 + mt * 16 + c.quad * 4 + reg) * NF + f];
        #pragma unroll
        for (int nt = 0; nt < 4; ++nt)
          #pragma unroll
          for (int reg = 0; reg < 4; ++reg) {
            const u32 w = x2p[mt][nt][reg >> 1];
            const float x2v = bf2f((reg & 1) ? (w >> 16) : (w & 0xffffu));
            const float gv = sigmoid_f(acc[mt][nt][reg] + bv[nt]);
            acc[mt][nt][reg] = gv * x2v + (1.0f - gv) * vr[reg];
          }
      }
      __syncthreads();   // all waves done reading sA (x2) before sRedF overlay
      ln_reduce8(c, sRedF, acc);
      float gm[4], bt[4];
      #pragma unroll
      for (int nt = 0; nt < 4; ++nt) {
        const int n = f * H + c.wid * 64 + nt * 16 + c.col;
        gm[nt] = gamma[n]; bt[nt] = beta[n];
      }
      #pragma unroll
      for (int mt = 0; mt < 4; ++mt)
        #pragma unroll
        for (int reg = 0; reg < 4; ++reg) {
          const int m = mt * 16 + c.quad * 4 + reg;
          float2 mr = *(float2*)&sRedF[1280 + m * 2];
          #pragma unroll
          for (int nt = 0; nt < 4; ++nt) {
            const float tv = gm[nt] * ((acc[mt][nt][reg] - mr.x) * mr.y) + bt[nt];
            outacc[mt][nt][reg] = fmaf(selw, tv, outacc[mt][nt][reg]);
          }
        }
      // prefetch next f's GEMM1 chunk0 slice (drained by the barrier below)
      if (f < NF - 1)
        stage_slice(c.wid, c.lane, W2p + (size_t)(f + 1) * 262144, sBw);
      __syncthreads();   // sRedF reads done before next f's A1 overwrites sA
    }
  }

  // store selected [MTOT, H]
  #pragma unroll
  for (int mt = 0; mt < 4; ++mt)
    #pragma unroll
    for (int reg = 0; reg < 4; ++reg) {
      const int m = row0 + mt * 16 + c.quad * 4 + reg;
      #pragma unroll
      for (int nt = 0; nt < 4; ++nt)
        out[(size_t)m * H + c.wid * 64 + nt * 16 + c.col] = outacc[mt][nt][reg];
    }
}

extern "C" void kernel_launch(void* const* d_in, const int* in_sizes, int n_in,
                              void* d_out, int out_size, void* d_ws, size_t ws_size,
                              hipStream_t stream) {
  const float* in_     = (const float*)d_in[0];
  const float* W1c     = (const float*)d_in[1];
  const float* b1c     = (const float*)d_in[2];
  const float* W2c     = (const float*)d_in[3];
  const float* b2c     = (const float*)d_in[4];
  const float* Wgc     = (const float*)d_in[5];
  const float* bgc     = (const float*)d_in[6];
  const float* gamma_c = (const float*)d_in[7];
  const float* beta_c  = (const float*)d_in[8];
  const float* Wsel    = (const float*)d_in[9];
  const float* bsel    = (const float*)d_in[10];
  const float* w1      = (const float*)d_in[11];
  const float* b1v     = (const float*)d_in[12];
  const float* W2      = (const float*)d_in[13];
  const float* b2v     = (const float*)d_in[14];
  const float* Wg      = (const float*)d_in[15];
  const float* bgv     = (const float*)d_in[16];
  const float* gma     = (const float*)d_in[17];
  const float* bta     = (const float*)d_in[18];

  float* out_sel = (float*)d_out;                      // [MTOT, H]
  float* out_w   = (float*)d_out + (size_t)MTOT * H;   // [B, T, 1, F]

  float* sel_ws = (float*)d_ws;                        // 4 KB
  u16*   W2p    = (u16*)((char*)d_ws + 4096);          // 2 MB
  u16*   Wgp    = W2p + (size_t)NF * H * H;            // 2 MB
  u16*   Cp     = Wgp + (size_t)NF * H * H;            // 1.5 MB (W1c|W2c|Wgc)
  u16*   x1g    = Cp + 3 * 262144;                     // 256 KB bf16 [256][512]
  u16*   xg     = x1g + 131072;                        // 256 KB bf16 [256][512]
  u32*   bar    = (u32*)(xg + 131072);                 // 2 barrier counters

  hipLaunchKernelGGL(pack_all, dim3(1408), dim3(256), 0, stream,
                     W2, Wg, W1c, W2c, Wgc, W2p, Wgp, Cp, bar);
  hipLaunchKernelGGL(ctx_fused, dim3(32), dim3(256), 0, stream,
                     in_, Cp, b1c, b2c, bgc, gamma_c, beta_c, Wsel, bsel,
                     x1g, xg, sel_ws, out_w, bar);
  hipLaunchKernelGGL(vsn_mfma, dim3(MTOT / 64), dim3(512), 0, stream,
                     in_, w1, b1v, b2v, bgv, gma, bta, W2p, Wgp, sel_ws, out_sel);
}